// Round 1
// baseline (68.329 us; speedup 1.0000x reference)
//
#include <hip/hip_runtime.h>

#define TILE 256

__global__ void prep_kernel(const float* __restrict__ pos,
                            const float* __restrict__ msx,
                            const float* __restrict__ msy,
                            const float* __restrict__ bpx,
                            const float* __restrict__ bpy,
                            const int*   __restrict__ midx,
                            int num_nodes, int m, int nb,
                            float* __restrict__ x, float* __restrict__ y,
                            float* __restrict__ sx, float* __restrict__ sy,
                            float* __restrict__ area,
                            float* __restrict__ accum, float* __restrict__ total) {
    const int N = m + nb;
    if (threadIdx.x == 0) { *accum = 0.0f; *total = 0.0f; }
    __syncthreads();
    // macro_idx is int64 in the reference; the harness may hand us int32 or
    // raw int64. Sorted indices guarantee idx[1] >= 1, so the odd int32
    // words are all zero iff the buffer is little-endian int64.
    bool is64 = (midx[1] == 0) && (midx[3] == 0) && (midx[5] == 0);
    float tsum = 0.0f;
    for (int i = threadIdx.x; i < N; i += blockDim.x) {
        float sxi = msx[i], syi = msy[i];
        float xi, yi;
        if (i < m) {
            int id = is64 ? midx[2 * i] : midx[i];
            xi = pos[id]             + 0.5f * sxi;
            yi = pos[num_nodes + id] + 0.5f * syi;
        } else {
            xi = bpx[i - m];
            yi = bpy[i - m];
        }
        x[i] = xi; y[i] = yi; sx[i] = sxi; sy[i] = syi;
        float a = sxi * syi;
        area[i] = a;
        tsum += a;
    }
    atomicAdd(total, tsum);
}

__global__ __launch_bounds__(TILE) void pairs_kernel(
        const float* __restrict__ x, const float* __restrict__ y,
        const float* __restrict__ sx, const float* __restrict__ sy,
        const float* __restrict__ area, int N,
        float* __restrict__ accum) {
    __shared__ float xs[TILE], ys[TILE], sxs[TILE], sys[TILE], as_[TILE];
    const int jt = blockIdx.y * TILE;
    {
        int j = jt + threadIdx.x;
        if (j < N) {
            xs[threadIdx.x]  = x[j];
            ys[threadIdx.x]  = y[j];
            sxs[threadIdx.x] = sx[j];
            sys[threadIdx.x] = sy[j];
            as_[threadIdx.x] = area[j];
        }
    }
    __syncthreads();

    const int i = blockIdx.x * TILE + threadIdx.x;
    float part = 0.0f;
    if (i < N) {
        const float xi = x[i], yi = y[i];
        const float sxi = sx[i], syi = sy[i], ai = area[i];
        const int nc = min(TILE, N - jt);
        for (int t = 0; t < nc; ++t) {
            float dx = fabsf(xi - xs[t]);
            float s  = 0.5f * (sxi + sxs[t]);
            if (dx <= s) {
                float r  = dx * __builtin_amdgcn_rcpf(s);
                float px = (dx <= 0.5f * s) ? fmaf(-2.0f * r, r, 1.0f)
                                            : 2.0f * (r - 1.0f) * (r - 1.0f);
                float dy = fabsf(yi - ys[t]);
                float s2 = 0.5f * (syi + sys[t]);
                if (dy <= s2) {
                    float ry = dy * __builtin_amdgcn_rcpf(s2);
                    float py = (dy <= 0.5f * s2) ? fmaf(-2.0f * ry, ry, 1.0f)
                                                 : 2.0f * (ry - 1.0f) * (ry - 1.0f);
                    part += (ai + as_[t]) * px * py;
                }
            }
        }
    }

    // wave (64-lane) shuffle reduce, then cross-wave via LDS
    for (int off = 32; off > 0; off >>= 1)
        part += __shfl_down(part, off, 64);
    __shared__ float wsum[TILE / 64];
    const int lane = threadIdx.x & 63;
    const int wid  = threadIdx.x >> 6;
    if (lane == 0) wsum[wid] = part;
    __syncthreads();
    if (threadIdx.x == 0) {
        float s = 0.0f;
        for (int w = 0; w < TILE / 64; ++w) s += wsum[w];
        atomicAdd(accum, s);
    }
}

__global__ void fin_kernel(const float* __restrict__ accum,
                           const float* __restrict__ total,
                           float* __restrict__ out) {
    float t = *total;
    // full symmetric sum = 2*triu + diag; diag_i = 2*area_i => diag = 2*t
    float triu = 0.5f * (*accum) - t;
    float l = triu / t;
    out[0] = l * l;
}

extern "C" void kernel_launch(void* const* d_in, const int* in_sizes, int n_in,
                              void* d_out, int out_size, void* d_ws, size_t ws_size,
                              hipStream_t stream) {
    const float* pos = (const float*)d_in[0];
    const float* msx = (const float*)d_in[1];
    const float* msy = (const float*)d_in[2];
    const float* bpx = (const float*)d_in[3];
    const float* bpy = (const float*)d_in[4];
    const int*  midx = (const int*)d_in[5];

    const int num_nodes = in_sizes[0] / 2;
    const int m  = in_sizes[5];          // movable macros (4000)
    const int nb = in_sizes[3];          // boundary nodes (252)
    const int N  = m + nb;

    float* ws    = (float*)d_ws;
    float* x     = ws + 0 * N;
    float* y     = ws + 1 * N;
    float* sx    = ws + 2 * N;
    float* sy    = ws + 3 * N;
    float* area  = ws + 4 * N;
    float* accum = ws + 5 * N;
    float* total = ws + 5 * N + 1;

    prep_kernel<<<1, 256, 0, stream>>>(pos, msx, msy, bpx, bpy, midx,
                                       num_nodes, m, nb,
                                       x, y, sx, sy, area, accum, total);

    const int T = (N + TILE - 1) / TILE;
    dim3 grid(T, T);
    pairs_kernel<<<grid, TILE, 0, stream>>>(x, y, sx, sy, area, N, accum);

    fin_kernel<<<1, 1, 0, stream>>>(accum, total, (float*)d_out);
}

// Round 2
// 58.253 us; speedup vs baseline: 1.1730x; 1.1730x over previous
//
#include <hip/hip_runtime.h>

#define BT   64   // threads per block (1 wave)
#define ROWS 4    // i-rows per thread
#define JT   64   // j-tile staged in LDS

__global__ __launch_bounds__(1024) void prep_kernel(
    const float* __restrict__ pos,
    const float* __restrict__ msx, const float* __restrict__ msy,
    const float* __restrict__ bpx, const float* __restrict__ bpy,
    const int*   __restrict__ midx,
    int num_nodes, int m, int nb,
    float4* __restrict__ p4, float* __restrict__ area,
    float* __restrict__ accum, float* __restrict__ total,
    unsigned* __restrict__ done)
{
    const int N = m + nb;
    if (threadIdx.x == 0) { *accum = 0.0f; *total = 0.0f; *done = 0u; }
    __syncthreads();
    // macro_idx is int64 in the reference; sorted => idx[1] >= 1, so odd
    // int32 words are all zero iff the buffer is little-endian int64.
    const bool is64 = (midx[1] == 0) && (midx[3] == 0) && (midx[5] == 0);
    float tsum = 0.0f;
    for (int i = threadIdx.x; i < N; i += blockDim.x) {
        float sxi = msx[i], syi = msy[i];
        float xi, yi;
        if (i < m) {
            int id = is64 ? midx[2 * i] : midx[i];
            xi = pos[id]             + 0.5f * sxi;
            yi = pos[num_nodes + id] + 0.5f * syi;
        } else {
            xi = bpx[i - m];
            yi = bpy[i - m];
        }
        p4[i] = make_float4(xi, yi, 0.5f * sxi, 0.5f * syi);
        float a = sxi * syi;
        area[i] = a;
        tsum += a;
    }
    for (int off = 32; off > 0; off >>= 1)
        tsum += __shfl_down(tsum, off, 64);
    if ((threadIdx.x & 63) == 0) atomicAdd(total, tsum);
}

// branchless piecewise-quadratic bell; relies on cndmask to discard the
// garbage lane values (inf etc.) produced by sentinel rows/cols
__device__ __forceinline__ float bell(float d, float s) {
    float r  = d * __builtin_amdgcn_rcpf(s);
    float nr = fmaf(-2.0f * r, r, 1.0f);
    float t  = r - 1.0f;
    float fr = (t + t) * t;
    float p  = (r <= 0.5f) ? nr : fr;
    return (r <= 1.0f) ? p : 0.0f;
}

__global__ __launch_bounds__(BT) void pairs_kernel(
    const float4* __restrict__ p4, const float* __restrict__ area,
    int N, int nblocks,
    float* __restrict__ accum, const float* __restrict__ total,
    unsigned* __restrict__ done, float* __restrict__ out)
{
    __shared__ float4 qj[JT];
    __shared__ float  aj[JT];
    const int jt = blockIdx.y * JT;
    {
        int j = jt + threadIdx.x;                 // BT == JT: one each
        if (j < N) { qj[threadIdx.x] = p4[j]; aj[threadIdx.x] = area[j]; }
        else       { qj[threadIdx.x] = make_float4(1e18f, 1e18f, 0.f, 0.f);
                     aj[threadIdx.x] = 0.f; }
    }
    float4 P[ROWS]; float A[ROWS];
    const int ibase = blockIdx.x * (BT * ROWS) + threadIdx.x;
    #pragma unroll
    for (int r = 0; r < ROWS; ++r) {
        int i = ibase + r * BT;
        if (i < N) { P[r] = p4[i]; A[r] = area[i]; }
        else       { P[r] = make_float4(-1e18f, -1e18f, 0.f, 0.f); A[r] = 0.f; }
    }
    __syncthreads();

    float part = 0.0f;
    #pragma unroll 8
    for (int t = 0; t < JT; ++t) {
        const float4 q = qj[t];
        const float aq = aj[t];
        #pragma unroll
        for (int r = 0; r < ROWS; ++r) {
            float dx = fabsf(P[r].x - q.x);
            float px = bell(dx, P[r].z + q.z);
            float dy = fabsf(P[r].y - q.y);
            float py = bell(dy, P[r].w + q.w);
            part = fmaf((A[r] + aq) * px, py, part);
        }
    }

    for (int off = 32; off > 0; off >>= 1)
        part += __shfl_down(part, off, 64);

    if (threadIdx.x == 0) {
        atomicAdd(accum, part);
        __threadfence();
        unsigned old = atomicAdd(done, 1u);
        if (old == (unsigned)(nblocks - 1)) {
            float full = atomicAdd(accum, 0.0f);   // coherent read-back
            float t = *total;
            // full = 2*triu + diag, diag_i = 2*area_i => diag = 2*total
            float triu = 0.5f * full - t;
            float l = triu / t;
            out[0] = l * l;
        }
    }
}

extern "C" void kernel_launch(void* const* d_in, const int* in_sizes, int n_in,
                              void* d_out, int out_size, void* d_ws, size_t ws_size,
                              hipStream_t stream) {
    const float* pos = (const float*)d_in[0];
    const float* msx = (const float*)d_in[1];
    const float* msy = (const float*)d_in[2];
    const float* bpx = (const float*)d_in[3];
    const float* bpy = (const float*)d_in[4];
    const int*  midx = (const int*)d_in[5];

    const int num_nodes = in_sizes[0] / 2;
    const int m  = in_sizes[5];          // 4000 movable macros
    const int nb = in_sizes[3];          // 252 boundary nodes
    const int N  = m + nb;

    float4* p4   = (float4*)d_ws;
    float* fws   = (float*)(p4 + N);
    float* area  = fws;
    float* accum = fws + N;
    float* total = fws + N + 1;
    unsigned* done = (unsigned*)(fws + N + 2);

    prep_kernel<<<1, 1024, 0, stream>>>(pos, msx, msy, bpx, bpy, midx,
                                        num_nodes, m, nb,
                                        p4, area, accum, total, done);

    const int gi = (N + BT * ROWS - 1) / (BT * ROWS);   // 17
    const int gj = (N + JT - 1) / JT;                   // 67
    dim3 grid(gi, gj);
    pairs_kernel<<<grid, BT, 0, stream>>>(p4, area, N, gi * gj,
                                          accum, total, done, (float*)d_out);
}

// Round 3
// 44.013 us; speedup vs baseline: 1.5525x; 1.3235x over previous
//
#include <hip/hip_runtime.h>

#define BT 256   // pairs block: 4 waves
#define JT 64    // j-tile per block

__global__ __launch_bounds__(256) void prep_kernel(
    const float* __restrict__ pos,
    const float* __restrict__ msx, const float* __restrict__ msy,
    const float* __restrict__ bpx, const float* __restrict__ bpy,
    const int*   __restrict__ midx,
    int num_nodes, int m, int N, int Npad,
    float4* __restrict__ p4, float* __restrict__ t_part,
    float* __restrict__ accum, unsigned* __restrict__ done)
{
    const int i = blockIdx.x * 256 + threadIdx.x;
    if (i == 0) { *accum = 0.0f; *done = 0u; }   // pairs runs after prep: no race
    // macro_idx is int64 in the reference; sorted => idx[1] >= 1, so the odd
    // int32 words are all zero iff the buffer is little-endian int64.
    const bool is64 = (midx[1] == 0) && (midx[3] == 0) && (midx[5] == 0);
    float a = 0.0f;
    float xi = 1e18f, yi = 1e18f, hx = 0.0f, hy = 0.0f;
    if (i < N) {
        hx = 0.5f * msx[i];
        hy = 0.5f * msy[i];
        if (i < m) {
            int id = is64 ? midx[2 * i] : midx[i];
            xi = pos[id]             + hx;
            yi = pos[num_nodes + id] + hy;
        } else {
            xi = bpx[i - m];
            yi = bpy[i - m];
        }
        a = 4.0f * hx * hy;
    }
    if (i < Npad) p4[i] = make_float4(xi, yi, hx, hy);

    // block-partial total area (no atomics)
    for (int off = 32; off > 0; off >>= 1) a += __shfl_down(a, off, 64);
    __shared__ float wpart[4];
    const int lane = threadIdx.x & 63, wid = threadIdx.x >> 6;
    if (lane == 0) wpart[wid] = a;
    __syncthreads();
    if (threadIdx.x == 0)
        t_part[blockIdx.x] = wpart[0] + wpart[1] + wpart[2] + wpart[3];
}

// branchless bell; NaN (sentinel-vs-sentinel 0*inf) fails both ordered
// compares and selects to 0
__device__ __forceinline__ float bell(float d, float s) {
    float r  = d * __builtin_amdgcn_rcpf(s);
    float nr = fmaf(-2.0f * r, r, 1.0f);
    float t  = r - 1.0f;
    float fr = (t + t) * t;
    float p  = (r <= 0.5f) ? nr : fr;
    return (r <= 1.0f) ? p : 0.0f;
}

__device__ __forceinline__ float pair_term(float4 P, float pai, float4 q) {
    float px = bell(fabsf(P.x - q.x), P.z + q.z);
    float py = bell(fabsf(P.y - q.y), P.w + q.w);
    float pq = q.z * q.w;
    return (pai + pq) * px * py;
}

__global__ __launch_bounds__(BT) void pairs_kernel(
    const float4* __restrict__ p4, int nblocks,
    float* __restrict__ accum, const float* __restrict__ t_part, int tparts,
    unsigned* __restrict__ done, float* __restrict__ out)
{
    const int i = blockIdx.x * BT + threadIdx.x;   // always < Npad (padded)
    const float4 P = p4[i];
    const float pai = P.z * P.w;
    const int jt = blockIdx.y * JT;

    float part0 = 0.0f, part1 = 0.0f;
    #pragma unroll 4
    for (int t = 0; t < JT; t += 2) {
        float4 q0 = p4[jt + t];       // wave-uniform address -> s_load
        float4 q1 = p4[jt + t + 1];
        part0 += pair_term(P, pai, q0);
        part1 += pair_term(P, pai, q1);
    }
    float part = part0 + part1;

    for (int off = 32; off > 0; off >>= 1)
        part += __shfl_down(part, off, 64);
    __shared__ float wsum[BT / 64];
    const int lane = threadIdx.x & 63, wid = threadIdx.x >> 6;
    if (lane == 0) wsum[wid] = part;
    __syncthreads();

    if (threadIdx.x == 0) {
        float s = wsum[0] + wsum[1] + wsum[2] + wsum[3];
        atomicAdd(accum, s);
        __threadfence();
        unsigned old = atomicAdd(done, 1u);
        if (old == (unsigned)(nblocks - 1)) {
            float T = 0.0f;
            for (int b = 0; b < tparts; ++b) T += t_part[b];
            float partsum = atomicAdd(accum, 0.0f);   // coherent read-back
            // S_full = 4*partsum = 2*triu + diag, diag = 2*T
            float triu = 2.0f * partsum - T;
            float l = triu / T;
            out[0] = l * l;
        }
    }
}

extern "C" void kernel_launch(void* const* d_in, const int* in_sizes, int n_in,
                              void* d_out, int out_size, void* d_ws, size_t ws_size,
                              hipStream_t stream) {
    const float* pos = (const float*)d_in[0];
    const float* msx = (const float*)d_in[1];
    const float* msy = (const float*)d_in[2];
    const float* bpx = (const float*)d_in[3];
    const float* bpy = (const float*)d_in[4];
    const int*  midx = (const int*)d_in[5];

    const int num_nodes = in_sizes[0] / 2;
    const int m  = in_sizes[5];          // 4000 movable macros
    const int nb = in_sizes[3];          // 252 boundary nodes
    const int N  = m + nb;

    const int gi = (N + BT - 1) / BT;    // 17
    const int gj = (N + JT - 1) / JT;    // 67
    const int Npad = (gi * BT > gj * JT) ? gi * BT : gj * JT;   // 4352

    float4* p4     = (float4*)d_ws;
    float*  t_part = (float*)(p4 + Npad);
    float*  accum  = t_part + gi;
    unsigned* done = (unsigned*)(accum + 1);

    prep_kernel<<<(Npad + 255) / 256, 256, 0, stream>>>(
        pos, msx, msy, bpx, bpy, midx, num_nodes, m, N, Npad,
        p4, t_part, accum, done);

    dim3 grid(gi, gj);
    pairs_kernel<<<grid, BT, 0, stream>>>(p4, gi * gj,
                                          accum, t_part, gi, done, (float*)d_out);
}

// Round 7
// 22.094 us; speedup vs baseline: 3.0926x; 1.9920x over previous
//
#include <hip/hip_runtime.h>

#define TI 64     // tile edge (i and j)
#define BT 256    // threads per pairs block (4 waves)

__global__ __launch_bounds__(256) void prep_kernel(
    const float* __restrict__ pos,
    const float* __restrict__ msx, const float* __restrict__ msy,
    const float* __restrict__ bpx, const float* __restrict__ bpy,
    const int*   __restrict__ midx,
    int num_nodes, int m, int N, int Npad,
    float4* __restrict__ p4, float* __restrict__ t_part)
{
    const int i = blockIdx.x * 256 + threadIdx.x;
    // macro_idx is int64 in the reference; sorted => idx[1] >= 1, so the odd
    // int32 words are all zero iff the buffer is little-endian int64.
    const bool is64 = (midx[1] == 0) && (midx[3] == 0) && (midx[5] == 0);
    float a = 0.0f;
    float xi = 1e18f, yi = 1e18f, hx = 0.0f, hy = 0.0f;
    if (i < N) {
        hx = 0.5f * msx[i];
        hy = 0.5f * msy[i];
        if (i < m) {
            int id = is64 ? midx[2 * i] : midx[i];
            xi = pos[id]             + hx;
            yi = pos[num_nodes + id] + hy;
        } else {
            xi = bpx[i - m];
            yi = bpy[i - m];
        }
        a = 4.0f * hx * hy;   // true area
    }
    if (i < Npad) p4[i] = make_float4(xi, yi, hx, hy);

    for (int off = 32; off > 0; off >>= 1) a += __shfl_down(a, off, 64);
    __shared__ float wpart[4];
    const int lane = threadIdx.x & 63, wid = threadIdx.x >> 6;
    if (lane == 0) wpart[wid] = a;
    __syncthreads();
    if (threadIdx.x == 0)
        t_part[blockIdx.x] = wpart[0] + wpart[1] + wpart[2] + wpart[3];
}

// branchless bell; NaN (sentinel self-pair: 0*inf) fails ordered compares -> 0
__device__ __forceinline__ float bell(float d, float s) {
    float r  = d * __builtin_amdgcn_rcpf(s);
    float nr = fmaf(-2.0f * r, r, 1.0f);
    float t  = r - 1.0f;
    float fr = (t + t) * t;
    float p  = (r <= 0.5f) ? nr : fr;
    return (r <= 1.0f) ? p : 0.0f;
}

__device__ __forceinline__ int tri_off(int ti, int T) {
    return ti * T - (ti * (ti - 1)) / 2;     // first block index of row ti
}

__global__ __launch_bounds__(BT) void pairs_kernel(
    const float4* __restrict__ p4, int T,
    float* __restrict__ partials)
{
    // decode linear block id -> (ti, tj) with ti <= tj
    const int b = blockIdx.x;
    const int w = 2 * T + 1;
    int ti = (int)(((float)w - sqrtf((float)(w * w - 8 * b))) * 0.5f);
    if (ti > T - 1) ti = T - 1;
    while (ti > 0 && tri_off(ti, T) > b) --ti;
    while (tri_off(ti + 1, T) <= b) ++ti;
    const int tj = ti + (b - tri_off(ti, T));

    __shared__ float4 qs[TI];
    if (threadIdx.x < TI) qs[threadIdx.x] = p4[tj * TI + threadIdx.x];
    __syncthreads();

    const int lane = threadIdx.x & 63, wid = threadIdx.x >> 6;
    const float4 P = p4[ti * TI + lane];
    const float pai = P.z * P.w;             // quarter-area

    float part = 0.0f;
    #pragma unroll
    for (int k = 0; k < 16; ++k) {
        const float4 q = qs[wid * 16 + k];   // wave-broadcast LDS read
        float px = bell(fabsf(P.x - q.x), P.z + q.z);
        float py = bell(fabsf(P.y - q.y), P.w + q.w);
        part = fmaf((pai + q.z * q.w) * px, py, part);
    }

    for (int off = 32; off > 0; off >>= 1)
        part += __shfl_down(part, off, 64);
    __shared__ float wsum[BT / 64];
    if (lane == 0) wsum[wid] = part;
    __syncthreads();
    if (threadIdx.x == 0) {
        float s = wsum[0] + wsum[1] + wsum[2] + wsum[3];
        partials[b] = (ti == tj) ? 0.5f * s : s;   // diagonal tiles half-weight
    }
}

__global__ __launch_bounds__(256) void fin_kernel(
    const float* __restrict__ partials, int np,
    const float* __restrict__ t_part, int nt,
    float* __restrict__ out)
{
    float s = 0.0f;
    for (int i = threadIdx.x; i < np; i += 256) s += partials[i];
    float t = 0.0f;
    for (int i = threadIdx.x; i < nt; i += 256) t += t_part[i];
    for (int off = 32; off > 0; off >>= 1) {
        s += __shfl_down(s, off, 64);
        t += __shfl_down(t, off, 64);
    }
    __shared__ float ws[4], wt[4];
    const int lane = threadIdx.x & 63, wid = threadIdx.x >> 6;
    if (lane == 0) { ws[wid] = s; wt[wid] = t; }
    __syncthreads();
    if (threadIdx.x == 0) {
        float S = ws[0] + ws[1] + ws[2] + ws[3];
        float T = wt[0] + wt[1] + wt[2] + wt[3];
        // partials are quarter-area scale: true pair-sum = 4*S = triu + T
        float triu = 4.0f * S - T;
        float l = triu / T;
        out[0] = l * l;
    }
}

extern "C" void kernel_launch(void* const* d_in, const int* in_sizes, int n_in,
                              void* d_out, int out_size, void* d_ws, size_t ws_size,
                              hipStream_t stream) {
    const float* pos = (const float*)d_in[0];
    const float* msx = (const float*)d_in[1];
    const float* msy = (const float*)d_in[2];
    const float* bpx = (const float*)d_in[3];
    const float* bpy = (const float*)d_in[4];
    const int*  midx = (const int*)d_in[5];

    const int num_nodes = in_sizes[0] / 2;
    const int m  = in_sizes[5];          // 4000 movable macros
    const int nb = in_sizes[3];          // 252 boundary nodes
    const int N  = m + nb;

    const int T    = (N + TI - 1) / TI;  // 68 tiles
    const int Npad = T * TI;             // 4352
    const int nblk = T * (T + 1) / 2;    // 2346 triangular tile-pairs
    const int gprep = (Npad + 255) / 256;

    float4* p4      = (float4*)d_ws;
    float*  t_part  = (float*)(p4 + Npad);
    float*  partials = t_part + gprep;

    prep_kernel<<<gprep, 256, 0, stream>>>(pos, msx, msy, bpx, bpy, midx,
                                           num_nodes, m, N, Npad, p4, t_part);

    pairs_kernel<<<nblk, BT, 0, stream>>>(p4, T, partials);

    fin_kernel<<<1, 256, 0, stream>>>(partials, nblk, t_part, gprep,
                                      (float*)d_out);
}